// Round 1
// baseline (21089.447 us; speedup 1.0000x reference)
//
#include <hip/hip_runtime.h>

#define NB 32
#define NZ 100
#define ST 20
#define HID 128
#define HW 32
#define PIX 1024
#define STEPS 64
#define TH 0.1f

// ---------------------------------------------------------------------------
// init: compute init_hidden = conv1x1(relu(conv1x1(z))) and scatter to center
// A must be pre-zeroed (hipMemsetAsync).
__global__ __launch_bounds__(64) void init_state_kernel(
    const float* __restrict__ z, const float* __restrict__ w1,
    const float* __restrict__ b1, const float* __restrict__ w2,
    const float* __restrict__ b2, float* __restrict__ A)
{
    __shared__ float zs[NZ];
    __shared__ float h1[50];
    const int n = blockIdx.x;
    const int t = threadIdx.x;
    for (int i = t; i < NZ; i += 64) zs[i] = z[n * NZ + i];
    __syncthreads();
    if (t < 50) {
        float a = b1[t];
        for (int i = 0; i < NZ; ++i) a += w1[t * NZ + i] * zs[i];
        h1[t] = fmaxf(a, 0.f);
    }
    __syncthreads();
    if (t < ST - 1) {
        float a = b2[t];
        for (int j = 0; j < 50; ++j) a += w2[t * 50 + j] * h1[j];
        A[n * ST * PIX + (t + 1) * PIX + 16 * HW + 16] = a;
    }
    if (t == 63) A[n * ST * PIX + 16 * HW + 16] = 0.5f;
}

// ---------------------------------------------------------------------------
// k1: fused perceive(3x3 conv 20->128) -> 1x1 128->128 relu -> 1x1 128->20
//     B = A + upd ; also writes pre-mask (maxpool3(A ch0) > TH)
// grid (16 strips, 32 batch), block 64 threads = 2 rows x 32 cols
__global__ __launch_bounds__(64) void step_update_kernel(
    const float* __restrict__ A, float* __restrict__ B, float* __restrict__ M,
    const float* __restrict__ Wp, const float* __restrict__ bp,
    const float* __restrict__ W1, const float* __restrict__ b1,
    const float* __restrict__ W2, const float* __restrict__ b2)
{
    __shared__ float tile[ST * 4 * 34];   // [c][tr 0..3][tc 0..33], zero padded
    __shared__ float perc[HID * 64];      // [i][pix] transposed (conflict-free)

    const int strip = blockIdx.x;         // 0..15  (2 rows each)
    const int n = blockIdx.y;
    const int tid = threadIdx.x;
    const int r0 = strip * 2;

    const float* An = A + n * ST * PIX;
    float* Bn = B + n * ST * PIX;

    // ---- stage state tile (rows r0-1 .. r0+2, cols -1..32) with zero pad
    for (int idx = tid; idx < ST * 4 * 34; idx += 64) {
        int tc = idx % 34;
        int tmp = idx / 34;
        int tr = tmp % 4;
        int c = tmp / 4;
        int row = r0 - 1 + tr;
        int col = tc - 1;
        float v = 0.f;
        if (row >= 0 && row < HW && col >= 0 && col < HW)
            v = An[c * PIX + row * HW + col];
        tile[idx] = v;
    }
    __syncthreads();

    const int ry = tid >> 5;   // 0/1
    const int x = tid & 31;
    const int y = r0 + ry;

    // ---- pre-living mask from A ch0 (zero pad is safe: 0 > 0.1 is false)
    {
        float mx = -1e30f;
        #pragma unroll
        for (int dy = 0; dy < 3; ++dy)
            #pragma unroll
            for (int dx = 0; dx < 3; ++dx)
                mx = fmaxf(mx, tile[(0 * 4 + ry + dy) * 34 + x + dx]);
        M[n * PIX + y * HW + x] = (mx > TH) ? 1.f : 0.f;
    }

    // ---- phase 1: perc[128] = 3x3 conv, in 4 chunks of 32 channels
    for (int kc = 0; kc < 4; ++kc) {
        float p[32];
        #pragma unroll
        for (int t = 0; t < 32; ++t) p[t] = bp[kc * 32 + t];
        for (int c = 0; c < ST; ++c) {
            float xv[9];
            #pragma unroll
            for (int dy = 0; dy < 3; ++dy)
                #pragma unroll
                for (int dx = 0; dx < 3; ++dx)
                    xv[dy * 3 + dx] = tile[(c * 4 + ry + dy) * 34 + x + dx];
            #pragma unroll
            for (int t = 0; t < 32; ++t) {
                const float* w = Wp + ((kc * 32 + t) * ST + c) * 9;  // uniform -> s_load
                #pragma unroll
                for (int q = 0; q < 9; ++q) p[t] += w[q] * xv[q];
            }
        }
        #pragma unroll
        for (int t = 0; t < 32; ++t) perc[(kc * 32 + t) * 64 + tid] = p[t];
    }
    // no barrier needed: each thread reads back only its own column

    // ---- phase 2: hid = relu(W1 @ perc + b1); upd = W2 @ hid + b2
    float upd[ST];
    #pragma unroll
    for (int o = 0; o < ST; ++o) upd[o] = b2[o];

    for (int jc = 0; jc < 4; ++jc) {
        float h[32];
        #pragma unroll
        for (int t = 0; t < 32; ++t) h[t] = b1[jc * 32 + t];
        for (int i = 0; i < HID; i += 4) {
            float pv0 = perc[(i + 0) * 64 + tid];
            float pv1 = perc[(i + 1) * 64 + tid];
            float pv2 = perc[(i + 2) * 64 + tid];
            float pv3 = perc[(i + 3) * 64 + tid];
            #pragma unroll
            for (int t = 0; t < 32; ++t) {
                const float* w = W1 + (jc * 32 + t) * HID + i;       // uniform -> s_load
                h[t] += w[0] * pv0 + w[1] * pv1 + w[2] * pv2 + w[3] * pv3;
            }
        }
        #pragma unroll
        for (int t = 0; t < 32; ++t) {
            float hv = fmaxf(h[t], 0.f);
            #pragma unroll
            for (int o = 0; o < ST; ++o)
                upd[o] += W2[o * HID + jc * 32 + t] * hv;            // uniform -> s_load
        }
    }

    // ---- B = A + upd
    #pragma unroll
    for (int c = 0; c < ST; ++c) {
        float a = tile[(c * 4 + ry + 1) * 34 + x + 1];
        Bn[c * PIX + y * HW + x] = a + upd[c];
    }
}

// ---------------------------------------------------------------------------
// k2: post-mask from B ch0, combine with pre-mask, write masked state to A
// grid (4, 32), block 256
__global__ __launch_bounds__(256) void step_mask_kernel(
    const float* __restrict__ B, const float* __restrict__ M,
    float* __restrict__ A)
{
    const int n = blockIdx.y;
    const int p = blockIdx.x * 256 + threadIdx.x;
    const int y = p >> 5;
    const int x = p & 31;
    const float* Bn = B + n * ST * PIX;
    float* An = A + n * ST * PIX;

    float m = 0.f;
    if (M[n * PIX + p] != 0.f) {
        float mx = -1e30f;
        for (int dy = -1; dy <= 1; ++dy) {
            int yy = y + dy;
            if (yy < 0 || yy >= HW) continue;
            for (int dx = -1; dx <= 1; ++dx) {
                int xx = x + dx;
                if (xx < 0 || xx >= HW) continue;
                mx = fmaxf(mx, Bn[yy * HW + xx]);
            }
        }
        if (mx > TH) m = 1.f;
    }
    #pragma unroll
    for (int c = 0; c < ST; ++c)
        An[c * PIX + p] = Bn[c * PIX + p] * m;
}

// ---------------------------------------------------------------------------
__global__ __launch_bounds__(256) void copy_out_kernel(
    const float* __restrict__ A, float* __restrict__ out)
{
    const int i = blockIdx.x * 256 + threadIdx.x;   // 32768
    const int n = i >> 10;
    const int p = i & 1023;
    out[i] = A[n * ST * PIX + p];
}

// ---------------------------------------------------------------------------
extern "C" void kernel_launch(void* const* d_in, const int* in_sizes, int n_in,
                              void* d_out, int out_size, void* d_ws, size_t ws_size,
                              hipStream_t stream)
{
    const float* z       = (const float*)d_in[0];
    const float* w_init1 = (const float*)d_in[1];
    const float* b_init1 = (const float*)d_in[2];
    const float* w_init2 = (const float*)d_in[3];
    const float* b_init2 = (const float*)d_in[4];
    const float* w_perc  = (const float*)d_in[5];
    const float* b_perc  = (const float*)d_in[6];
    const float* w_up1   = (const float*)d_in[7];
    const float* b_up1   = (const float*)d_in[8];
    const float* w_up2   = (const float*)d_in[9];
    const float* b_up2   = (const float*)d_in[10];

    float* A = (float*)d_ws;                       // 32*20*1024 floats
    float* B = A + NB * ST * PIX;
    float* M = B + NB * ST * PIX;                  // 32*1024 floats

    hipMemsetAsync(A, 0, (size_t)NB * ST * PIX * sizeof(float), stream);
    init_state_kernel<<<NB, 64, 0, stream>>>(z, w_init1, b_init1, w_init2, b_init2, A);

    for (int s = 0; s < STEPS; ++s) {
        step_update_kernel<<<dim3(16, NB), 64, 0, stream>>>(
            A, B, M, w_perc, b_perc, w_up1, b_up1, w_up2, b_up2);
        step_mask_kernel<<<dim3(4, NB), 256, 0, stream>>>(B, M, A);
    }
    copy_out_kernel<<<128, 256, 0, stream>>>(A, (float*)d_out);
}

// Round 2
// 4389.006 us; speedup vs baseline: 4.8051x; 4.8051x over previous
//
#include <hip/hip_runtime.h>

#define NB 32
#define NZ 100
#define ST 20
#define HID 128
#define HW 32
#define PIX 1024
#define STEPS 64
#define TH 0.1f

// ---------------------------------------------------------------------------
// init: init_hidden = conv1x1(relu(conv1x1(z))) scattered to center; M := 1
// B must be pre-zeroed (hipMemsetAsync).
__global__ __launch_bounds__(64) void init_state_kernel(
    const float* __restrict__ z, const float* __restrict__ w1,
    const float* __restrict__ b1, const float* __restrict__ w2,
    const float* __restrict__ b2, float* __restrict__ B,
    unsigned char* __restrict__ M)
{
    __shared__ float zs[NZ];
    __shared__ float h1[50];
    const int n = blockIdx.x;
    const int t = threadIdx.x;
    for (int i = t; i < NZ; i += 64) zs[i] = z[n * NZ + i];
    __syncthreads();
    if (t < 50) {
        float a = b1[t];
        for (int i = 0; i < NZ; ++i) a += w1[t * NZ + i] * zs[i];
        h1[t] = fmaxf(a, 0.f);
    }
    __syncthreads();
    if (t < ST - 1) {
        float a = b2[t];
        for (int j = 0; j < 50; ++j) a += w2[t * 50 + j] * h1[j];
        B[n * ST * PIX + (t + 1) * PIX + 16 * HW + 16] = a;
    }
    if (t == 63) B[n * ST * PIX + 16 * HW + 16] = 0.5f;
    for (int i = t; i < PIX; i += 64) M[n * PIX + i] = 1;
}

// ---------------------------------------------------------------------------
// Fused CA step. Input: Bin = S' (unmasked post-add), Min = pre-mask bits.
// Computes A = Bin*(Min & postmask(Bin)) in LDS, Mout = premask(A),
// upd = up2(relu(up1(perc3x3(A)))), Bout = A + upd.
// Block: 512 thr = 8 waves; lane = pixel (2 rows x 32 cols), wave = 16-chan chunk.
// Grid: (16 row-strips, 32 images). Weight indices SGPR-uniform via
// readfirstlane(waveId) -> s_load broadcast, FMA with scalar operand.
__global__ __launch_bounds__(512, 4) void ca_step_kernel(
    const float* __restrict__ Bin, const unsigned char* __restrict__ Min,
    float* __restrict__ Bout, unsigned char* __restrict__ Mout,
    const float* __restrict__ Wp, const float* __restrict__ bp,
    const float* __restrict__ W1, const float* __restrict__ b1,
    const float* __restrict__ W2, const float* __restrict__ b2)
{
    __shared__ float bch0[6 * 36];       // B ch0, halo 2
    __shared__ float m4[136];            // combined mask over tile region 4x34
    __shared__ float tile[ST * 136];     // masked state A, [c][tr0..3][tc0..33]
    __shared__ float uni[8 * 20 * 64];   // perc[128][64] (32KB) / updS[8][20][64] (40KB)

    const int strip = blockIdx.x;
    const int n = blockIdx.y;
    const int tid = threadIdx.x;
    const int r0 = strip * 2;
    const float* Bn = Bin + n * ST * PIX;

    // ---- stage B ch0 with halo 2 (rows r0-2..r0+3, cols -2..33), zero pad
    if (tid < 216) {
        int r = tid / 36, cq = tid % 36;
        int row = r0 - 2 + r, col = cq - 2;
        float v = 0.f;
        if (row >= 0 && row < HW && col >= 0 && col < HW) v = Bn[row * HW + col];
        bch0[tid] = v;
    }
    __syncthreads();

    // ---- combined mask m4 = Min & (maxpool3(B ch0) > TH) over tile region
    if (tid < 136) {
        int tr = tid / 34, tc = tid % 34;
        int y = r0 - 1 + tr, xc = tc - 1;
        float m = 0.f;
        if (y >= 0 && y < HW && xc >= 0 && xc < HW) {
            if (Min[n * PIX + y * HW + xc]) {
                float mx = -1e30f;
                #pragma unroll
                for (int dy = 0; dy < 3; ++dy)
                    #pragma unroll
                    for (int dx = 0; dx < 3; ++dx)
                        mx = fmaxf(mx, bch0[(tr + dy) * 36 + tc + dx]);
                if (mx > TH) m = 1.f;
            }
        }
        m4[tid] = m;
    }
    __syncthreads();

    // ---- stage masked state A = Bin * m4 (all 20 channels, halo 1)
    for (int idx = tid; idx < ST * 136; idx += 512) {
        int c = idx / 136, rem = idx % 136;
        int tr = rem / 34, tc = rem % 34;
        int y = r0 - 1 + tr, xc = tc - 1;
        float v = 0.f;
        if (y >= 0 && y < HW && xc >= 0 && xc < HW)
            v = Bn[c * PIX + y * HW + xc] * m4[rem];
        tile[idx] = v;
    }
    __syncthreads();

    const int wv = __builtin_amdgcn_readfirstlane(tid >> 6);  // SGPR wave id
    const int lane = tid & 63;
    const int ry = lane >> 5;
    const int x = lane & 31;

    // ---- wave 0: next step's pre-mask from A ch0
    if (tid < 64) {
        float mx = -1e30f;
        #pragma unroll
        for (int dy = 0; dy < 3; ++dy)
            #pragma unroll
            for (int dx = 0; dx < 3; ++dx)
                mx = fmaxf(mx, tile[(ry + dy) * 34 + x + dx]);
        Mout[n * PIX + (r0 + ry) * HW + x] = (mx > TH) ? 1 : 0;
    }

    // ---- phase 1: perceive 3x3 conv, this wave's 16 output channels
    float p[16];
    #pragma unroll
    for (int t = 0; t < 16; ++t) p[t] = bp[wv * 16 + t];
    for (int c = 0; c < ST; ++c) {
        float xv[9];
        #pragma unroll
        for (int dy = 0; dy < 3; ++dy)
            #pragma unroll
            for (int dx = 0; dx < 3; ++dx)
                xv[dy * 3 + dx] = tile[(c * 4 + ry + dy) * 34 + x + dx];
        #pragma unroll
        for (int t = 0; t < 16; ++t) {
            const float* w = Wp + ((wv * 16 + t) * ST + c) * 9;   // s_load
            #pragma unroll
            for (int q = 0; q < 9; ++q) p[t] += w[q] * xv[q];
        }
    }
    float* perc = uni;
    #pragma unroll
    for (int t = 0; t < 16; ++t) perc[(wv * 16 + t) * 64 + lane] = p[t];
    __syncthreads();

    // ---- phase 2: hid = relu(W1 @ perc + b1), this wave's 16 channels
    float h[16];
    #pragma unroll
    for (int t = 0; t < 16; ++t) h[t] = b1[wv * 16 + t];
    for (int i = 0; i < HID; i += 4) {
        float pv0 = perc[(i + 0) * 64 + lane];
        float pv1 = perc[(i + 1) * 64 + lane];
        float pv2 = perc[(i + 2) * 64 + lane];
        float pv3 = perc[(i + 3) * 64 + lane];
        #pragma unroll
        for (int t = 0; t < 16; ++t) {
            const float* w = W1 + (wv * 16 + t) * HID + i;        // s_load
            h[t] += w[0] * pv0 + w[1] * pv1 + w[2] * pv2 + w[3] * pv3;
        }
    }

    // ---- phase 3: partial upd over this wave's 16 hid channels (registers)
    float u[ST];
    #pragma unroll
    for (int c = 0; c < ST; ++c) u[c] = 0.f;
    #pragma unroll
    for (int t = 0; t < 16; ++t) {
        float hv = fmaxf(h[t], 0.f);
        #pragma unroll
        for (int c = 0; c < ST; ++c)
            u[c] += W2[c * HID + wv * 16 + t] * hv;               // s_load
    }
    __syncthreads();                       // all perc reads done (WAR on uni)
    float* updS = uni;
    #pragma unroll
    for (int c = 0; c < ST; ++c) updS[(wv * 20 + c) * 64 + lane] = u[c];
    __syncthreads();

    // ---- reduce 8 partials + bias + A, write Bout = S'
    float* Bo = Bout + n * ST * PIX;
    for (int idx = tid; idx < ST * 64; idx += 512) {
        int c = idx >> 6, px = idx & 63;
        int py = px >> 5, pxx = px & 31;
        float s = b2[c];
        #pragma unroll
        for (int w = 0; w < 8; ++w) s += updS[(w * 20 + c) * 64 + px];
        s += tile[(c * 4 + py + 1) * 34 + pxx + 1];
        Bo[c * PIX + (r0 + py) * HW + pxx] = s;
    }
}

// ---------------------------------------------------------------------------
// finalize: out ch0 = B * (M & postmask(B))
__global__ __launch_bounds__(256) void finalize_kernel(
    const float* __restrict__ B, const unsigned char* __restrict__ M,
    float* __restrict__ out)
{
    const int n = blockIdx.y;
    const int p = blockIdx.x * 256 + threadIdx.x;
    const int y = p >> 5, x = p & 31;
    const float* Bn = B + n * ST * PIX;
    float m = 0.f;
    if (M[n * PIX + p]) {
        float mx = -1e30f;
        for (int dy = -1; dy <= 1; ++dy) {
            int yy = y + dy; if (yy < 0 || yy >= HW) continue;
            for (int dx = -1; dx <= 1; ++dx) {
                int xx = x + dx; if (xx < 0 || xx >= HW) continue;
                mx = fmaxf(mx, Bn[yy * HW + xx]);
            }
        }
        if (mx > TH) m = 1.f;
    }
    out[n * PIX + p] = Bn[p] * m;
}

// ---------------------------------------------------------------------------
extern "C" void kernel_launch(void* const* d_in, const int* in_sizes, int n_in,
                              void* d_out, int out_size, void* d_ws, size_t ws_size,
                              hipStream_t stream)
{
    const float* z       = (const float*)d_in[0];
    const float* w_init1 = (const float*)d_in[1];
    const float* b_init1 = (const float*)d_in[2];
    const float* w_init2 = (const float*)d_in[3];
    const float* b_init2 = (const float*)d_in[4];
    const float* w_perc  = (const float*)d_in[5];
    const float* b_perc  = (const float*)d_in[6];
    const float* w_up1   = (const float*)d_in[7];
    const float* b_up1   = (const float*)d_in[8];
    const float* w_up2   = (const float*)d_in[9];
    const float* b_up2   = (const float*)d_in[10];

    float* B0 = (float*)d_ws;                         // 32*20*1024 f32
    float* B1 = B0 + NB * ST * PIX;
    unsigned char* M0 = (unsigned char*)(B1 + NB * ST * PIX);
    unsigned char* M1 = M0 + NB * PIX;

    hipMemsetAsync(B0, 0, (size_t)NB * ST * PIX * sizeof(float), stream);
    init_state_kernel<<<NB, 64, 0, stream>>>(z, w_init1, b_init1, w_init2,
                                             b_init2, B0, M0);

    for (int s = 0; s < STEPS; ++s) {
        const float* bi = (s & 1) ? B1 : B0;
        float* bo       = (s & 1) ? B0 : B1;
        const unsigned char* mi = (s & 1) ? M1 : M0;
        unsigned char* mo       = (s & 1) ? M0 : M1;
        ca_step_kernel<<<dim3(16, NB), 512, 0, stream>>>(
            bi, mi, bo, mo, w_perc, b_perc, w_up1, b_up1, w_up2, b_up2);
    }
    // 64 steps (even) -> final state in (B0, M0)
    finalize_kernel<<<dim3(4, NB), 256, 0, stream>>>(B0, M0, (float*)d_out);
}

// Round 4
// 1051.208 us; speedup vs baseline: 20.0621x; 4.1752x over previous
//
#include <hip/hip_runtime.h>

#define NB 32
#define NZ 100
#define ST 20
#define HID 128
#define HW 32
#define PIX 1024
#define STEPS 64
#define TH 0.1f
#define SCL 0.0625f     // 1/16 stored-value scaling (power of 2)
#define ISCL 16.0f

typedef _Float16 half8  __attribute__((ext_vector_type(8)));
typedef _Float16 half4v __attribute__((ext_vector_type(4)));
typedef float    floatx4 __attribute__((ext_vector_type(4)));

// perceive GEMM K layout: k = q*24 + c  (q=dy*3+dx in 0..8, c in 0..23, pad from 20)
// K = 224 -> 7 k-steps of 32; k >= 216 (q==9) reads a zeroed LDS line.
#define NKS1 7
#define PK 136          // perc/hid LDS row stride (+8 pad: kills 16-way bank conflict)

// ---------------------------------------------------------------------------
__global__ __launch_bounds__(64) void init_state_kernel(
    const float* __restrict__ z, const float* __restrict__ w1,
    const float* __restrict__ b1, const float* __restrict__ w2,
    const float* __restrict__ b2, float* __restrict__ B,
    unsigned char* __restrict__ M)
{
    __shared__ float zs[NZ];
    __shared__ float h1[50];
    const int n = blockIdx.x;
    const int t = threadIdx.x;
    for (int i = t; i < NZ; i += 64) zs[i] = z[n * NZ + i];
    __syncthreads();
    if (t < 50) {
        float a = b1[t];
        for (int i = 0; i < NZ; ++i) a += w1[t * NZ + i] * zs[i];
        h1[t] = fmaxf(a, 0.f);
    }
    __syncthreads();
    if (t < ST - 1) {
        float a = b2[t];
        for (int j = 0; j < 50; ++j) a += w2[t * 50 + j] * h1[j];
        B[n * ST * PIX + (t + 1) * PIX + 16 * HW + 16] = a;
    }
    if (t == 63) B[n * ST * PIX + 16 * HW + 16] = 0.5f;
    for (int i = t; i < PIX; i += 64) M[n * PIX + i] = 1;
}

// ---------------------------------------------------------------------------
// Repack weights into MFMA A-fragment order as fp16 hi/lo pairs.
// WpR*: [w 0..7][ks 0..6][lane][j]  m=w*16+(lane&15), k=ks*32+quad*8+j,
//        k -> (q=k/24, c=k%24), src = Wp[m][c][q] if q<9 && c<20 else 0
// W1R*: [w 0..7][ks 0..3][lane][j]  k straight 0..127
// W2R*: [mt 0..1][ks 0..3][lane][j] m=mt*16+(lane&15) (0 if m>=20)
__global__ __launch_bounds__(256) void repack_kernel(
    const float* __restrict__ Wp, const float* __restrict__ W1,
    const float* __restrict__ W2,
    _Float16* __restrict__ WpRh, _Float16* __restrict__ WpRl,
    _Float16* __restrict__ W1Rh, _Float16* __restrict__ W1Rl,
    _Float16* __restrict__ W2Rh, _Float16* __restrict__ W2Rl)
{
    int e = blockIdx.x * 256 + threadIdx.x;
    if (e < 28672) {
        int j = e & 7, lane = (e >> 3) & 63, t2 = e >> 9;   // t2 = w*7+ks
        int ks = t2 % 7, w = t2 / 7;
        int m = w * 16 + (lane & 15);
        int k = ks * 32 + ((lane >> 4) << 3) + j;
        int q = k / 24, c = k - q * 24;
        float v = (q < 9 && c < ST) ? Wp[m * 180 + c * 9 + q] : 0.f;
        _Float16 hi = (_Float16)v;
        WpRh[e] = hi; WpRl[e] = (_Float16)(v - (float)hi);
    } else if (e < 45056) {
        int e2 = e - 28672;
        int j = e2 & 7, lane = (e2 >> 3) & 63, t2 = e2 >> 9; // t2 = w*4+ks
        int ks = t2 & 3, w = t2 >> 2;
        int m = w * 16 + (lane & 15);
        int k = ks * 32 + ((lane >> 4) << 3) + j;
        float v = W1[m * 128 + k];
        _Float16 hi = (_Float16)v;
        W1Rh[e2] = hi; W1Rl[e2] = (_Float16)(v - (float)hi);
    } else if (e < 49152) {
        int e3 = e - 45056;
        int j = e3 & 7, lane = (e3 >> 3) & 63, t2 = e3 >> 9; // t2 = mt*4+ks
        int ks = t2 & 3, mt = t2 >> 2;
        int m = mt * 16 + (lane & 15);
        int k = ks * 32 + ((lane >> 4) << 3) + j;
        float v = (m < ST) ? W2[m * 128 + k] : 0.f;
        _Float16 hi = (_Float16)v;
        W2Rh[e3] = hi; W2Rl[e3] = (_Float16)(v - (float)hi);
    }
}

// ---------------------------------------------------------------------------
// Fused CA step (split-fp16 MFMA). Bin = S' (unmasked), Min = pre-mask bits.
// A = Bin*(Min & postmask(Bin)); Mout = premask(A);
// perc = Wp@im2col(A); hid = relu(W1@perc+b1); upd = W2@hid+b2; Bout = A+upd.
// All GEMM operands stored as fp16 (hi,lo) pairs of value/16.
__global__ __launch_bounds__(512, 4) void ca_step_kernel(
    const float* __restrict__ Bin, const unsigned char* __restrict__ Min,
    float* __restrict__ Bout, unsigned char* __restrict__ Mout,
    const _Float16* __restrict__ WpRh, const _Float16* __restrict__ WpRl,
    const float* __restrict__ bp,
    const _Float16* __restrict__ W1Rh, const _Float16* __restrict__ W1Rl,
    const float* __restrict__ b1,
    const _Float16* __restrict__ W2Rh, const _Float16* __restrict__ W2Rl,
    const float* __restrict__ b2)
{
    __shared__ float bch0[216];                       // B ch0, halo 2
    __shared__ float m4[136];                         // combined mask, 4x34
    __shared__ float ch0f[136];                       // masked A ch0 (f32)
    __shared__ __align__(16) _Float16 tTh[4 * 34 * 24];  // state/16 hi, [pix][c]
    __shared__ __align__(16) _Float16 tTl[4 * 34 * 24];  // state/16 lo
    __shared__ __align__(16) _Float16 zero16[8];
    __shared__ __align__(16) _Float16 pH[64 * PK];    // perc/16 hi -> later hid/16 hi
    __shared__ __align__(16) _Float16 pL[64 * PK];    // perc/16 lo -> later hid/16 lo

    const int strip = blockIdx.x;
    const int n = blockIdx.y;
    const int tid = threadIdx.x;
    const int r0 = strip * 2;
    const float* Bn = Bin + n * ST * PIX;

    const int wv = __builtin_amdgcn_readfirstlane(tid >> 6);
    const int lane = tid & 63;
    const int col = lane & 15;
    const int quad = lane >> 4;

    // ---- prefetch G1 A-frags (global, L2-hot; overlaps all staging)
    half8 aPh[NKS1], aPl[NKS1];
    #pragma unroll
    for (int ks = 0; ks < NKS1; ++ks) {
        aPh[ks] = *(const half8*)(WpRh + ((wv * 7 + ks) * 64 + lane) * 8);
        aPl[ks] = *(const half8*)(WpRl + ((wv * 7 + ks) * 64 + lane) * 8);
    }
    floatx4 biasP = *(const floatx4*)(bp + wv * 16 + quad * 4) * SCL;

    // ---- stage B ch0 with halo 2
    if (tid < 216) {
        int r = tid / 36, cq = tid % 36;
        int row = r0 - 2 + r, colg = cq - 2;
        float v = 0.f;
        if (row >= 0 && row < HW && colg >= 0 && colg < HW) v = Bn[row * HW + colg];
        bch0[tid] = v;
    }
    if (tid < 8) zero16[tid] = (_Float16)0.f;
    __syncthreads();

    // ---- combined mask m4 = Min & (maxpool3(B ch0) > TH); masked ch0 f32
    if (tid < 136) {
        int tr = tid / 34, tc = tid % 34;
        int y = r0 - 1 + tr, xc = tc - 1;
        float m = 0.f;
        if (y >= 0 && y < HW && xc >= 0 && xc < HW) {
            if (Min[n * PIX + y * HW + xc]) {
                float mx = -1e30f;
                #pragma unroll
                for (int dy = 0; dy < 3; ++dy)
                    #pragma unroll
                    for (int dx = 0; dx < 3; ++dx)
                        mx = fmaxf(mx, bch0[(tr + dy) * 36 + tc + dx]);
                if (mx > TH) m = 1.f;
            }
        }
        m4[tid] = m;
        ch0f[tid] = bch0[(tr + 1) * 36 + (tc + 1)] * m;
    }
    __syncthreads();

    // ---- wave 0: next step's pre-mask from masked A ch0 (f32 — no rounding)
    if (tid < 64) {
        int ry = lane >> 5, xx = lane & 31;
        float mx = -1e30f;
        #pragma unroll
        for (int dy = 0; dy < 3; ++dy)
            #pragma unroll
            for (int dx = 0; dx < 3; ++dx)
                mx = fmaxf(mx, ch0f[(ry + dy) * 34 + xx + dx]);
        Mout[n * PIX + (r0 + ry) * HW + xx] = (mx > TH) ? 1 : 0;
    }

    // ---- stage transposed masked state/16 as fp16 hi/lo: tT[pix][c]
    for (int idx = tid; idx < 3264; idx += 512) {
        int c = idx % 24;
        int pix = idx / 24;                 // tr*34+tc
        float v = 0.f;
        if (c < ST) {
            int tr = pix / 34, tc = pix - tr * 34;
            int y = r0 - 1 + tr, xc = tc - 1;
            if (y >= 0 && y < HW && xc >= 0 && xc < HW)
                v = Bn[c * PIX + y * HW + xc] * m4[pix];
        }
        float xs = v * SCL;
        _Float16 hi = (_Float16)xs;
        tTh[idx] = hi;
        tTl[idx] = (_Float16)(xs - (float)hi);
    }
    __syncthreads();

    // ---- per-(ks,quad) fragment offset in tT; ks=6,quad=3 -> zero line
    int koff[NKS1];
    #pragma unroll
    for (int ks = 0; ks < NKS1; ++ks) {
        int k0 = ks * 32 + quad * 8;
        int q = k0 / 24, c0 = k0 - q * 24;
        int dy = q / 3, dx = q - dy * 3;
        koff[ks] = (q < 9) ? (dy * 34 + dx) * 24 + c0 : -1;
    }

    // ---- GEMM 1: perc/16 = Wp @ tT (3-product split), store hi/lo to pH/pL
    #pragma unroll
    for (int nt = 0; nt < 4; ++nt) {
        const int px = nt * 16 + col;
        const int pb = ((px >> 5) * 34 + (px & 31)) * 24;
        floatx4 acc = biasP;
        #pragma unroll
        for (int ks = 0; ks < NKS1; ++ks) {
            const _Float16* sh = (koff[ks] >= 0) ? (tTh + pb + koff[ks]) : zero16;
            const _Float16* sl = (koff[ks] >= 0) ? (tTl + pb + koff[ks]) : zero16;
            half8 bh = *(const half8*)sh;
            half8 bl = *(const half8*)sl;
            acc = __builtin_amdgcn_mfma_f32_16x16x32_f16(aPh[ks], bh, acc, 0, 0, 0);
            acc = __builtin_amdgcn_mfma_f32_16x16x32_f16(aPh[ks], bl, acc, 0, 0, 0);
            acc = __builtin_amdgcn_mfma_f32_16x16x32_f16(aPl[ks], bh, acc, 0, 0, 0);
        }
        _Float16 h[4], l[4];
        #pragma unroll
        for (int r = 0; r < 4; ++r) {
            h[r] = (_Float16)acc[r];
            l[r] = (_Float16)(acc[r] - (float)h[r]);
        }
        const int mb = wv * 16 + quad * 4;
        *(half4v*)&pH[px * PK + mb] = (half4v){h[0], h[1], h[2], h[3]};
        *(half4v*)&pL[px * PK + mb] = (half4v){l[0], l[1], l[2], l[3]};
    }
    __syncthreads();

    // ---- GEMM 2: hid/16 = relu(W1 @ perc + b1)/16
    half8 aHh[4], aHl[4];
    #pragma unroll
    for (int ks = 0; ks < 4; ++ks) {
        aHh[ks] = *(const half8*)(W1Rh + ((wv * 4 + ks) * 64 + lane) * 8);
        aHl[ks] = *(const half8*)(W1Rl + ((wv * 4 + ks) * 64 + lane) * 8);
    }
    floatx4 biasH = *(const floatx4*)(b1 + wv * 16 + quad * 4) * SCL;
    floatx4 accs[4];
    #pragma unroll
    for (int nt = 0; nt < 4; ++nt) {
        const int px = nt * 16 + col;
        floatx4 acc = biasH;
        #pragma unroll
        for (int ks = 0; ks < 4; ++ks) {
            half8 bh = *(const half8*)&pH[px * PK + ks * 32 + quad * 8];
            half8 bl = *(const half8*)&pL[px * PK + ks * 32 + quad * 8];
            acc = __builtin_amdgcn_mfma_f32_16x16x32_f16(aHh[ks], bh, acc, 0, 0, 0);
            acc = __builtin_amdgcn_mfma_f32_16x16x32_f16(aHh[ks], bl, acc, 0, 0, 0);
            acc = __builtin_amdgcn_mfma_f32_16x16x32_f16(aHl[ks], bh, acc, 0, 0, 0);
        }
        accs[nt] = acc;
    }
    __syncthreads();                        // all perc reads complete
    #pragma unroll
    for (int nt = 0; nt < 4; ++nt) {
        const int px = nt * 16 + col;
        _Float16 h[4], l[4];
        #pragma unroll
        for (int r = 0; r < 4; ++r) {
            float hv = fmaxf(accs[nt][r], 0.f);   // relu commutes with /16
            h[r] = (_Float16)hv;
            l[r] = (_Float16)(hv - (float)h[r]);
        }
        const int mb = wv * 16 + quad * 4;
        *(half4v*)&pH[px * PK + mb] = (half4v){h[0], h[1], h[2], h[3]};
        *(half4v*)&pL[px * PK + mb] = (half4v){l[0], l[1], l[2], l[3]};
    }
    __syncthreads();

    // ---- GEMM 3: upd = 16*(W2 @ hid/16) + b2; Bout = A + upd
    const int mt = wv & 1, ntU = wv >> 1;
    half8 aUh[4], aUl[4];
    #pragma unroll
    for (int ks = 0; ks < 4; ++ks) {
        aUh[ks] = *(const half8*)(W2Rh + ((mt * 4 + ks) * 64 + lane) * 8);
        aUl[ks] = *(const half8*)(W2Rl + ((mt * 4 + ks) * 64 + lane) * 8);
    }
    floatx4 accU = {0.f, 0.f, 0.f, 0.f};
    const int pxU = ntU * 16 + col;
    #pragma unroll
    for (int ks = 0; ks < 4; ++ks) {
        half8 bh = *(const half8*)&pH[pxU * PK + ks * 32 + quad * 8];
        half8 bl = *(const half8*)&pL[pxU * PK + ks * 32 + quad * 8];
        accU = __builtin_amdgcn_mfma_f32_16x16x32_f16(aUh[ks], bh, accU, 0, 0, 0);
        accU = __builtin_amdgcn_mfma_f32_16x16x32_f16(aUh[ks], bl, accU, 0, 0, 0);
        accU = __builtin_amdgcn_mfma_f32_16x16x32_f16(aUl[ks], bh, accU, 0, 0, 0);
    }
    const int py = pxU >> 5, pxx = pxU & 31;
    const float mval = m4[(py + 1) * 34 + pxx + 1];
    float* Bo = Bout + n * ST * PIX;
    #pragma unroll
    for (int r = 0; r < 4; ++r) {
        int m = mt * 16 + quad * 4 + r;
        if (m < ST) {
            float a = Bn[m * PIX + (r0 + py) * HW + pxx] * mval;
            Bo[m * PIX + (r0 + py) * HW + pxx] = a + ISCL * accU[r] + b2[m];
        }
    }
}

// ---------------------------------------------------------------------------
__global__ __launch_bounds__(256) void finalize_kernel(
    const float* __restrict__ B, const unsigned char* __restrict__ M,
    float* __restrict__ out)
{
    const int n = blockIdx.y;
    const int p = blockIdx.x * 256 + threadIdx.x;
    const int y = p >> 5, x = p & 31;
    const float* Bn = B + n * ST * PIX;
    float m = 0.f;
    if (M[n * PIX + p]) {
        float mx = -1e30f;
        for (int dy = -1; dy <= 1; ++dy) {
            int yy = y + dy; if (yy < 0 || yy >= HW) continue;
            for (int dx = -1; dx <= 1; ++dx) {
                int xx = x + dx; if (xx < 0 || xx >= HW) continue;
                mx = fmaxf(mx, Bn[yy * HW + xx]);
            }
        }
        if (mx > TH) m = 1.f;
    }
    out[n * PIX + p] = Bn[p] * m;
}

// ---------------------------------------------------------------------------
extern "C" void kernel_launch(void* const* d_in, const int* in_sizes, int n_in,
                              void* d_out, int out_size, void* d_ws, size_t ws_size,
                              hipStream_t stream)
{
    const float* z       = (const float*)d_in[0];
    const float* w_init1 = (const float*)d_in[1];
    const float* b_init1 = (const float*)d_in[2];
    const float* w_init2 = (const float*)d_in[3];
    const float* b_init2 = (const float*)d_in[4];
    const float* w_perc  = (const float*)d_in[5];
    const float* b_perc  = (const float*)d_in[6];
    const float* w_up1   = (const float*)d_in[7];
    const float* b_up1   = (const float*)d_in[8];
    const float* w_up2   = (const float*)d_in[9];
    const float* b_up2   = (const float*)d_in[10];

    float* B0 = (float*)d_ws;                          // 655360 f32
    float* B1 = B0 + NB * ST * PIX;
    unsigned char* M0 = (unsigned char*)(B1 + NB * ST * PIX);
    unsigned char* M1 = M0 + NB * PIX;
    _Float16* WpRh = (_Float16*)(M1 + NB * PIX);       // 28672 each
    _Float16* WpRl = WpRh + 28672;
    _Float16* W1Rh = WpRl + 28672;                     // 16384 each
    _Float16* W1Rl = W1Rh + 16384;
    _Float16* W2Rh = W1Rl + 16384;                     // 4096 each
    _Float16* W2Rl = W2Rh + 4096;

    repack_kernel<<<192, 256, 0, stream>>>(w_perc, w_up1, w_up2,
                                           WpRh, WpRl, W1Rh, W1Rl, W2Rh, W2Rl);
    hipMemsetAsync(B0, 0, (size_t)NB * ST * PIX * sizeof(float), stream);
    init_state_kernel<<<NB, 64, 0, stream>>>(z, w_init1, b_init1, w_init2,
                                             b_init2, B0, M0);

    for (int s = 0; s < STEPS; ++s) {
        const float* bi = (s & 1) ? B1 : B0;
        float* bo       = (s & 1) ? B0 : B1;
        const unsigned char* mi = (s & 1) ? M1 : M0;
        unsigned char* mo       = (s & 1) ? M0 : M1;
        ca_step_kernel<<<dim3(16, NB), 512, 0, stream>>>(
            bi, mi, bo, mo, WpRh, WpRl, b_perc, W1Rh, W1Rl, b_up1,
            W2Rh, W2Rl, b_up2);
    }
    // 64 steps (even) -> final state in (B0, M0)
    finalize_kernel<<<dim3(4, NB), 256, 0, stream>>>(B0, M0, (float*)d_out);
}

// Round 5
// 995.410 us; speedup vs baseline: 21.1867x; 1.0561x over previous
//
#include <hip/hip_runtime.h>

#define NB 32
#define NZ 100
#define ST 20
#define HID 128
#define HW 32
#define PIX 1024
#define STEPS 64
#define TH 0.1f
#define SCL 0.0625f     // 1/16 stored-value scaling (power of 2)
#define ISCL 16.0f

typedef _Float16 half8  __attribute__((ext_vector_type(8)));
typedef _Float16 half4v __attribute__((ext_vector_type(4)));
typedef float    floatx4 __attribute__((ext_vector_type(4)));

// perceive GEMM K layout: k = q*24 + c  (q=dy*3+dx in 0..8, c in 0..23, pad from 20)
// K = 224 -> 7 k-steps of 32; k >= 216 (q==9) reads a zeroed LDS line.
#define NKS1 7
#define PK 136          // perc/hid LDS row stride (+8 pad: kills 16-way bank conflict)

// ---------------------------------------------------------------------------
__global__ __launch_bounds__(64) void init_state_kernel(
    const float* __restrict__ z, const float* __restrict__ w1,
    const float* __restrict__ b1, const float* __restrict__ w2,
    const float* __restrict__ b2, float* __restrict__ B,
    unsigned char* __restrict__ M)
{
    __shared__ float zs[NZ];
    __shared__ float h1[50];
    const int n = blockIdx.x;
    const int t = threadIdx.x;
    for (int i = t; i < NZ; i += 64) zs[i] = z[n * NZ + i];
    __syncthreads();
    if (t < 50) {
        float a = b1[t];
        for (int i = 0; i < NZ; ++i) a += w1[t * NZ + i] * zs[i];
        h1[t] = fmaxf(a, 0.f);
    }
    __syncthreads();
    if (t < ST - 1) {
        float a = b2[t];
        for (int j = 0; j < 50; ++j) a += w2[t * 50 + j] * h1[j];
        B[n * ST * PIX + (t + 1) * PIX + 16 * HW + 16] = a;
    }
    if (t == 63) B[n * ST * PIX + 16 * HW + 16] = 0.5f;
    for (int i = t; i < PIX; i += 64) M[n * PIX + i] = 1;
}

// ---------------------------------------------------------------------------
// Repack weights into MFMA A-fragment order as fp16 hi/lo pairs. (unchanged)
__global__ __launch_bounds__(256) void repack_kernel(
    const float* __restrict__ Wp, const float* __restrict__ W1,
    const float* __restrict__ W2,
    _Float16* __restrict__ WpRh, _Float16* __restrict__ WpRl,
    _Float16* __restrict__ W1Rh, _Float16* __restrict__ W1Rl,
    _Float16* __restrict__ W2Rh, _Float16* __restrict__ W2Rl)
{
    int e = blockIdx.x * 256 + threadIdx.x;
    if (e < 28672) {
        int j = e & 7, lane = (e >> 3) & 63, t2 = e >> 9;   // t2 = w*7+ks
        int ks = t2 % 7, w = t2 / 7;
        int m = w * 16 + (lane & 15);
        int k = ks * 32 + ((lane >> 4) << 3) + j;
        int q = k / 24, c = k - q * 24;
        float v = (q < 9 && c < ST) ? Wp[m * 180 + c * 9 + q] : 0.f;
        _Float16 hi = (_Float16)v;
        WpRh[e] = hi; WpRl[e] = (_Float16)(v - (float)hi);
    } else if (e < 45056) {
        int e2 = e - 28672;
        int j = e2 & 7, lane = (e2 >> 3) & 63, t2 = e2 >> 9; // t2 = w*4+ks
        int ks = t2 & 3, w = t2 >> 2;
        int m = w * 16 + (lane & 15);
        int k = ks * 32 + ((lane >> 4) << 3) + j;
        float v = W1[m * 128 + k];
        _Float16 hi = (_Float16)v;
        W1Rh[e2] = hi; W1Rl[e2] = (_Float16)(v - (float)hi);
    } else if (e < 49152) {
        int e3 = e - 45056;
        int j = e3 & 7, lane = (e3 >> 3) & 63, t2 = e3 >> 9; // t2 = mt*4+ks
        int ks = t2 & 3, mt = t2 >> 2;
        int m = mt * 16 + (lane & 15);
        int k = ks * 32 + ((lane >> 4) << 3) + j;
        float v = (m < ST) ? W2[m * 128 + k] : 0.f;
        _Float16 hi = (_Float16)v;
        W2Rh[e3] = hi; W2Rl[e3] = (_Float16)(v - (float)hi);
    }
}

// ---------------------------------------------------------------------------
// Fused CA step (split-fp16 MFMA, 4Mx2N wave tiling, streamed A-frags).
__global__ __launch_bounds__(512, 4) void ca_step_kernel(
    const float* __restrict__ Bin, const unsigned char* __restrict__ Min,
    float* __restrict__ Bout, unsigned char* __restrict__ Mout,
    const _Float16* __restrict__ WpRh, const _Float16* __restrict__ WpRl,
    const float* __restrict__ bp,
    const _Float16* __restrict__ W1Rh, const _Float16* __restrict__ W1Rl,
    const float* __restrict__ b1,
    const _Float16* __restrict__ W2Rh, const _Float16* __restrict__ W2Rl,
    const float* __restrict__ b2)
{
    __shared__ float bch0[216];                       // B ch0, halo 2
    __shared__ float m4[136];                         // combined mask, 4x34
    __shared__ float ch0f[136];                       // masked A ch0 (f32)
    __shared__ __align__(16) _Float16 tTh[4 * 34 * 24];  // state/16 hi, [pix][c]
    __shared__ __align__(16) _Float16 tTl[4 * 34 * 24];  // state/16 lo
    __shared__ __align__(16) _Float16 zero16[8];
    __shared__ __align__(16) _Float16 pH[64 * PK];    // perc/16 hi -> later hid/16 hi
    __shared__ __align__(16) _Float16 pL[64 * PK];    // perc/16 lo -> later hid/16 lo

    const int strip = blockIdx.x;
    const int n = blockIdx.y;
    const int tid = threadIdx.x;
    const int r0 = strip * 2;
    const float* Bn = Bin + n * ST * PIX;

    const int wv = __builtin_amdgcn_readfirstlane(tid >> 6);
    const int lane = tid & 63;
    const int col = lane & 15;
    const int quad = lane >> 4;
    const int wm = wv >> 1;            // 0..3 : M-split (2 m-tiles each)
    const int wn = wv & 1;             // 0..1 : N-split (2 n-tiles each)

    // ---- stage B ch0 with halo 2
    if (tid < 216) {
        int r = tid / 36, cq = tid % 36;
        int row = r0 - 2 + r, colg = cq - 2;
        float v = 0.f;
        if (row >= 0 && row < HW && colg >= 0 && colg < HW) v = Bn[row * HW + colg];
        bch0[tid] = v;
    }
    if (tid < 8) zero16[tid] = (_Float16)0.f;
    __syncthreads();

    // ---- combined mask m4 = Min & (maxpool3(B ch0) > TH); masked ch0 f32
    if (tid < 136) {
        int tr = tid / 34, tc = tid % 34;
        int y = r0 - 1 + tr, xc = tc - 1;
        float m = 0.f;
        if (y >= 0 && y < HW && xc >= 0 && xc < HW) {
            if (Min[n * PIX + y * HW + xc]) {
                float mx = -1e30f;
                #pragma unroll
                for (int dy = 0; dy < 3; ++dy)
                    #pragma unroll
                    for (int dx = 0; dx < 3; ++dx)
                        mx = fmaxf(mx, bch0[(tr + dy) * 36 + tc + dx]);
                if (mx > TH) m = 1.f;
            }
        }
        m4[tid] = m;
        ch0f[tid] = bch0[(tr + 1) * 36 + (tc + 1)] * m;
    }
    __syncthreads();

    // ---- wave 0: next step's pre-mask from masked A ch0 (f32 — no rounding)
    if (tid < 64) {
        int ry = lane >> 5, xx = lane & 31;
        float mx = -1e30f;
        #pragma unroll
        for (int dy = 0; dy < 3; ++dy)
            #pragma unroll
            for (int dx = 0; dx < 3; ++dx)
                mx = fmaxf(mx, ch0f[(ry + dy) * 34 + xx + dx]);
        Mout[n * PIX + (r0 + ry) * HW + xx] = (mx > TH) ? 1 : 0;
    }

    // ---- stage transposed masked state/16 as fp16 hi/lo: tT[pix][c]
    for (int idx = tid; idx < 3264; idx += 512) {
        int c = idx % 24;
        int pix = idx / 24;                 // tr*34+tc
        float v = 0.f;
        if (c < ST) {
            int tr = pix / 34, tc = pix - tr * 34;
            int y = r0 - 1 + tr, xc = tc - 1;
            if (y >= 0 && y < HW && xc >= 0 && xc < HW)
                v = Bn[c * PIX + y * HW + xc] * m4[pix];
        }
        float xs = v * SCL;
        _Float16 hi = (_Float16)xs;
        tTh[idx] = hi;
        tTl[idx] = (_Float16)(xs - (float)hi);
    }
    __syncthreads();

    // ---- per-(ks,quad) fragment offset in tT; invalid -> zero line
    int koff[NKS1];
    #pragma unroll
    for (int ks = 0; ks < NKS1; ++ks) {
        int k0 = ks * 32 + quad * 8;
        int q = k0 / 24, c0 = k0 - q * 24;
        int dy = q / 3, dx = q - dy * 3;
        koff[ks] = (q < 9) ? (dy * 34 + dx) * 24 + c0 : -1;
    }
    // per-n-tile pixel base in tT
    int pbase[2];
    #pragma unroll
    for (int j = 0; j < 2; ++j) {
        int px = (wn * 2 + j) * 16 + col;
        pbase[j] = ((px >> 5) * 34 + (px & 31)) * 24;
    }

    // ---- GEMM 1: perc/16 = Wp @ tT, 2m x 2n per wave, A streamed from L2
    floatx4 acc1[2][2];
    #pragma unroll
    for (int i = 0; i < 2; ++i) {
        floatx4 b = *(const floatx4*)(bp + (wm * 2 + i) * 16 + quad * 4) * SCL;
        acc1[i][0] = b; acc1[i][1] = b;
    }
    #pragma unroll
    for (int ks = 0; ks < NKS1; ++ks) {
        half8 Ah[2], Al[2];
        #pragma unroll
        for (int i = 0; i < 2; ++i) {
            int mt = wm * 2 + i;
            Ah[i] = *(const half8*)(WpRh + ((mt * 7 + ks) * 64 + lane) * 8);
            Al[i] = *(const half8*)(WpRl + ((mt * 7 + ks) * 64 + lane) * 8);
        }
        half8 bh[2], bl[2];
        #pragma unroll
        for (int j = 0; j < 2; ++j) {
            const _Float16* sh = (koff[ks] >= 0) ? (tTh + pbase[j] + koff[ks]) : zero16;
            const _Float16* sl = (koff[ks] >= 0) ? (tTl + pbase[j] + koff[ks]) : zero16;
            bh[j] = *(const half8*)sh;
            bl[j] = *(const half8*)sl;
        }
        #pragma unroll
        for (int i = 0; i < 2; ++i)
            #pragma unroll
            for (int j = 0; j < 2; ++j) {
                acc1[i][j] = __builtin_amdgcn_mfma_f32_16x16x32_f16(Ah[i], bh[j], acc1[i][j], 0, 0, 0);
                acc1[i][j] = __builtin_amdgcn_mfma_f32_16x16x32_f16(Ah[i], bl[j], acc1[i][j], 0, 0, 0);
                acc1[i][j] = __builtin_amdgcn_mfma_f32_16x16x32_f16(Al[i], bh[j], acc1[i][j], 0, 0, 0);
            }
    }
    #pragma unroll
    for (int i = 0; i < 2; ++i)
        #pragma unroll
        for (int j = 0; j < 2; ++j) {
            const int px = (wn * 2 + j) * 16 + col;
            const int mb = (wm * 2 + i) * 16 + quad * 4;
            _Float16 h[4], l[4];
            #pragma unroll
            for (int r = 0; r < 4; ++r) {
                h[r] = (_Float16)acc1[i][j][r];
                l[r] = (_Float16)(acc1[i][j][r] - (float)h[r]);
            }
            *(half4v*)&pH[px * PK + mb] = (half4v){h[0], h[1], h[2], h[3]};
            *(half4v*)&pL[px * PK + mb] = (half4v){l[0], l[1], l[2], l[3]};
        }
    __syncthreads();

    // ---- GEMM 2: hid/16 = relu(W1 @ perc + b1)/16, 2m x 2n, A streamed
    floatx4 acc2[2][2];
    #pragma unroll
    for (int i = 0; i < 2; ++i) {
        floatx4 b = *(const floatx4*)(b1 + (wm * 2 + i) * 16 + quad * 4) * SCL;
        acc2[i][0] = b; acc2[i][1] = b;
    }
    #pragma unroll
    for (int ks = 0; ks < 4; ++ks) {
        half8 Ah[2], Al[2];
        #pragma unroll
        for (int i = 0; i < 2; ++i) {
            int mt = wm * 2 + i;
            Ah[i] = *(const half8*)(W1Rh + ((mt * 4 + ks) * 64 + lane) * 8);
            Al[i] = *(const half8*)(W1Rl + ((mt * 4 + ks) * 64 + lane) * 8);
        }
        half8 bh[2], bl[2];
        #pragma unroll
        for (int j = 0; j < 2; ++j) {
            const int px = (wn * 2 + j) * 16 + col;
            bh[j] = *(const half8*)&pH[px * PK + ks * 32 + quad * 8];
            bl[j] = *(const half8*)&pL[px * PK + ks * 32 + quad * 8];
        }
        #pragma unroll
        for (int i = 0; i < 2; ++i)
            #pragma unroll
            for (int j = 0; j < 2; ++j) {
                acc2[i][j] = __builtin_amdgcn_mfma_f32_16x16x32_f16(Ah[i], bh[j], acc2[i][j], 0, 0, 0);
                acc2[i][j] = __builtin_amdgcn_mfma_f32_16x16x32_f16(Ah[i], bl[j], acc2[i][j], 0, 0, 0);
                acc2[i][j] = __builtin_amdgcn_mfma_f32_16x16x32_f16(Al[i], bh[j], acc2[i][j], 0, 0, 0);
            }
    }
    __syncthreads();                        // all perc reads complete
    #pragma unroll
    for (int i = 0; i < 2; ++i)
        #pragma unroll
        for (int j = 0; j < 2; ++j) {
            const int px = (wn * 2 + j) * 16 + col;
            const int mb = (wm * 2 + i) * 16 + quad * 4;
            _Float16 h[4], l[4];
            #pragma unroll
            for (int r = 0; r < 4; ++r) {
                float hv = fmaxf(acc2[i][j][r], 0.f);   // relu commutes with /16
                h[r] = (_Float16)hv;
                l[r] = (_Float16)(hv - (float)h[r]);
            }
            *(half4v*)&pH[px * PK + mb] = (half4v){h[0], h[1], h[2], h[3]};
            *(half4v*)&pL[px * PK + mb] = (half4v){l[0], l[1], l[2], l[3]};
        }
    __syncthreads();

    // ---- GEMM 3: upd = 16*(W2 @ hid/16) + b2; Bout = A + upd; A streamed
    const int mt3 = wv & 1, ntU = wv >> 1;
    floatx4 accU = {0.f, 0.f, 0.f, 0.f};
    const int pxU = ntU * 16 + col;
    #pragma unroll
    for (int ks = 0; ks < 4; ++ks) {
        half8 aUh = *(const half8*)(W2Rh + ((mt3 * 4 + ks) * 64 + lane) * 8);
        half8 aUl = *(const half8*)(W2Rl + ((mt3 * 4 + ks) * 64 + lane) * 8);
        half8 bh = *(const half8*)&pH[pxU * PK + ks * 32 + quad * 8];
        half8 bl = *(const half8*)&pL[pxU * PK + ks * 32 + quad * 8];
        accU = __builtin_amdgcn_mfma_f32_16x16x32_f16(aUh, bh, accU, 0, 0, 0);
        accU = __builtin_amdgcn_mfma_f32_16x16x32_f16(aUh, bl, accU, 0, 0, 0);
        accU = __builtin_amdgcn_mfma_f32_16x16x32_f16(aUl, bh, accU, 0, 0, 0);
    }
    const int py = pxU >> 5, pxx = pxU & 31;
    const float mval = m4[(py + 1) * 34 + pxx + 1];
    float* Bo = Bout + n * ST * PIX;
    #pragma unroll
    for (int r = 0; r < 4; ++r) {
        int m = mt3 * 16 + quad * 4 + r;
        if (m < ST) {
            float a = Bn[m * PIX + (r0 + py) * HW + pxx] * mval;
            Bo[m * PIX + (r0 + py) * HW + pxx] = a + ISCL * accU[r] + b2[m];
        }
    }
}

// ---------------------------------------------------------------------------
__global__ __launch_bounds__(256) void finalize_kernel(
    const float* __restrict__ B, const unsigned char* __restrict__ M,
    float* __restrict__ out)
{
    const int n = blockIdx.y;
    const int p = blockIdx.x * 256 + threadIdx.x;
    const int y = p >> 5, x = p & 31;
    const float* Bn = B + n * ST * PIX;
    float m = 0.f;
    if (M[n * PIX + p]) {
        float mx = -1e30f;
        for (int dy = -1; dy <= 1; ++dy) {
            int yy = y + dy; if (yy < 0 || yy >= HW) continue;
            for (int dx = -1; dx <= 1; ++dx) {
                int xx = x + dx; if (xx < 0 || xx >= HW) continue;
                mx = fmaxf(mx, Bn[yy * HW + xx]);
            }
        }
        if (mx > TH) m = 1.f;
    }
    out[n * PIX + p] = Bn[p] * m;
}

// ---------------------------------------------------------------------------
extern "C" void kernel_launch(void* const* d_in, const int* in_sizes, int n_in,
                              void* d_out, int out_size, void* d_ws, size_t ws_size,
                              hipStream_t stream)
{
    const float* z       = (const float*)d_in[0];
    const float* w_init1 = (const float*)d_in[1];
    const float* b_init1 = (const float*)d_in[2];
    const float* w_init2 = (const float*)d_in[3];
    const float* b_init2 = (const float*)d_in[4];
    const float* w_perc  = (const float*)d_in[5];
    const float* b_perc  = (const float*)d_in[6];
    const float* w_up1   = (const float*)d_in[7];
    const float* b_up1   = (const float*)d_in[8];
    const float* w_up2   = (const float*)d_in[9];
    const float* b_up2   = (const float*)d_in[10];

    float* B0 = (float*)d_ws;                          // 655360 f32
    float* B1 = B0 + NB * ST * PIX;
    unsigned char* M0 = (unsigned char*)(B1 + NB * ST * PIX);
    unsigned char* M1 = M0 + NB * PIX;
    _Float16* WpRh = (_Float16*)(M1 + NB * PIX);       // 28672 each
    _Float16* WpRl = WpRh + 28672;
    _Float16* W1Rh = WpRl + 28672;                     // 16384 each
    _Float16* W1Rl = W1Rh + 16384;
    _Float16* W2Rh = W1Rl + 16384;                     // 4096 each
    _Float16* W2Rl = W2Rh + 4096;

    repack_kernel<<<192, 256, 0, stream>>>(w_perc, w_up1, w_up2,
                                           WpRh, WpRl, W1Rh, W1Rl, W2Rh, W2Rl);
    hipMemsetAsync(B0, 0, (size_t)NB * ST * PIX * sizeof(float), stream);
    init_state_kernel<<<NB, 64, 0, stream>>>(z, w_init1, b_init1, w_init2,
                                             b_init2, B0, M0);

    for (int s = 0; s < STEPS; ++s) {
        const float* bi = (s & 1) ? B1 : B0;
        float* bo       = (s & 1) ? B0 : B1;
        const unsigned char* mi = (s & 1) ? M1 : M0;
        unsigned char* mo       = (s & 1) ? M0 : M1;
        ca_step_kernel<<<dim3(16, NB), 512, 0, stream>>>(
            bi, mi, bo, mo, WpRh, WpRl, b_perc, W1Rh, W1Rl, b_up1,
            W2Rh, W2Rl, b_up2);
    }
    // 64 steps (even) -> final state in (B0, M0)
    finalize_kernel<<<dim3(4, NB), 256, 0, stream>>>(B0, M0, (float*)d_out);
}